// Round 17
// baseline (205.117 us; speedup 1.0000x reference)
//
#include <hip/hip_runtime.h>

// FusedGromovWasserstein — 3 kernels:
//  prep_w32: W1,W2 f32 -> bf16-hi 32x32x16-MFMA B-fragments in d_ws
//  fgw_proj: 4 batches/block, 512 thr; wave wid = colgroup, all 4 batches
//            (per ks: 1 W L2-load amortized over 4 A ds_reads + 4 MFMA);
//            mfma_32x32x16 (x-hi, W-hi); cvt_pk; (row&15) XOR swizzle;
//            G+C tail in waves 0-3 (one batch each, early exit for rest).
//  fgw_sink: 1 wave/batch, barrier-free, 8 blocks/CU; base-2 log domain,
//            static E factor (1 exp2 per u-phase); xor16/xor32 reduces.
// Outputs flat: [sigmoid(-cost) 8192][T 8192*256][C 8192*256][cost 8192].

#define OFF_T   8192
#define OFF_C   2105344
#define OFF_CST 4202496

typedef float  f32x4  __attribute__((ext_vector_type(4)));
typedef float  f32x16 __attribute__((ext_vector_type(16)));
typedef short  s16x8  __attribute__((ext_vector_type(8)));

#define LOG2E 1.4426950408889634f

// native v_exp_f32 (2^x) / v_log_f32 (log2 x)
__device__ __forceinline__ float fexp2(float x) { return __builtin_amdgcn_exp2f(x); }
__device__ __forceinline__ float flog2(float x) { return __builtin_amdgcn_logf(x); }

// v_cvt_pk_bf16_f32: RNE, 1 VALU for 2 values (no builtin on gfx950 — T12)
__device__ __forceinline__ unsigned int cvt_pk_bf16(float lo, float hi) {
  unsigned int r;
  asm("v_cvt_pk_bf16_f32 %0, %1, %2" : "=v"(r) : "v"(lo), "v"(hi));
  return r;
}
__device__ __forceinline__ unsigned short cvt_bf16(float x) {
  unsigned int r;
  asm("v_cvt_pk_bf16_f32 %0, %1, %2" : "=v"(r) : "v"(x), "v"(x));
  return (unsigned short)r;
}

// ---- cross-lane reduction helpers ----
template <int CTRL>
__device__ __forceinline__ float dpp_add(float x) {
  return x + __int_as_float(__builtin_amdgcn_update_dpp(
      0, __float_as_int(x), CTRL, 0xf, 0xf, true));
}
template <int CTRL>
__device__ __forceinline__ float dpp_max(float x) {
  return fmaxf(x, __int_as_float(__builtin_amdgcn_update_dpp(
      0, __float_as_int(x), CTRL, 0xf, 0xf, true)));
}
__device__ __forceinline__ float row16_sum(float x) {
  x = dpp_add<0xB1>(x);  x = dpp_add<0x4E>(x);
  x = dpp_add<0x124>(x); x = dpp_add<0x128>(x);
  return x;
}
__device__ __forceinline__ float row16_max(float x) {
  x = dpp_max<0xB1>(x);  x = dpp_max<0x4E>(x);
  x = dpp_max<0x124>(x); x = dpp_max<0x128>(x);
  return x;
}
__device__ __forceinline__ float xor16_add(float x) {
  return x + __int_as_float(__builtin_amdgcn_ds_swizzle(__float_as_int(x), 0x401F));
}
__device__ __forceinline__ float xor16_max(float x) {
  return fmaxf(x, __int_as_float(__builtin_amdgcn_ds_swizzle(__float_as_int(x), 0x401F)));
}
__device__ __forceinline__ float xor32_add(float x) { return x + __shfl_xor(x, 32); }
__device__ __forceinline__ float xor32_max(float x) { return fmaxf(x, __shfl_xor(x, 32)); }

// ---------------------------------------------------------------------------
// prep_w32: 16384 hi fragments (2 layers x 16 ksteps x 8 colgroups x 64 lanes).
// Fragment fid holds W[col = cg*32 + (lane&31)][k = s*16 + (lane>>5)*8 + e].
__global__ __launch_bounds__(256, 1)
void prep_w32(const float* __restrict__ W1, const float* __restrict__ W2,
              unsigned int* __restrict__ wh)
{
  const int fid  = blockIdx.x * 256 + threadIdx.x;   // 0..16383
  const int l    = fid >> 13;
  const int s    = (fid >> 9) & 15;
  const int cg   = (fid >> 6) & 7;
  const int lane = fid & 63;
  const int col  = cg * 32 + (lane & 31);
  const int k0   = s * 16 + ((lane >> 5) << 3);
  const float* W = l ? W2 : W1;
  const float* src = W + ((size_t)col << 8) + k0;
  float4 a = *(const float4*)src;
  float4 b = *(const float4*)(src + 4);
  uint4 vh = {cvt_pk_bf16(a.x, a.y), cvt_pk_bf16(a.z, a.w),
              cvt_pk_bf16(b.x, b.y), cvt_pk_bf16(b.z, b.w)};
  ((uint4*)wh)[fid] = vh;
}

// ---------------------------------------------------------------------------
// fgw_proj: 4 batches/block, 512 threads (8 waves). LDS: 4 x 16KB x-hi tiles
// (rows 0-15 q, 16-31 r; row stride 512B; XOR swizzle ((row&15)<<4)),
// normL [4][8][32] f32 at float idx 16384.
// Wave wid = colgroup; per ks: 1 W L2-load + 4 A ds_reads + 4 MFMA.
// Tail: waves 0-3 full G + C for one batch each.
__global__ __launch_bounds__(512, 2)
void fgw_proj(const float* __restrict__ g_q,  const float* __restrict__ g_r,
              const unsigned short* __restrict__ wh,
              const float* __restrict__ g_b1, const float* __restrict__ g_b2,
              float* __restrict__ g_out)
{
  __shared__ __align__(16) float smemf[17408];   // 69,632 B -> 2 blocks/CU
  char* sm = (char*)smemf;
  float* normL = smemf + 16384;                  // [4][8][32]
  const int bId0 = blockIdx.x * 4;
  const int tid  = threadIdx.x;
  const int lane = tid & 63, wid = tid >> 6;     // wid 0..7 = colgroup
  const int cl   = lane & 31, half = lane >> 5;  // A-row / D-col, k-half

  // ---- stage 4 batches as bf16-hi; non-temporal (read-once stream) ----
  #pragma unroll
  for (int j = 0; j < 8; ++j) {
    int idx = (j << 9) + tid;          // 0..4095
    int bb  = idx >> 10;
    int t   = idx & 1023;
    int r   = t >> 6;                  // row 0..15
    int sg  = t & 63;                  // float4 segment
    int off = ((sg << 3) ^ ((r & 15) << 4));
    char* xb = sm + bb * 16384;
    const f32x4* xq = (const f32x4*)(g_q + (size_t)(bId0 + bb) * 4096 + (r << 8) + (sg << 2));
    const f32x4* xr = (const f32x4*)(g_r + (size_t)(bId0 + bb) * 4096 + (r << 8) + (sg << 2));
    f32x4 v0 = __builtin_nontemporal_load(xq);
    f32x4 v1 = __builtin_nontemporal_load(xr);
    {
      unsigned int* ph = (unsigned int*)(xb + r * 512 + off);
      ph[0] = cvt_pk_bf16(v0[0], v0[1]);
      ph[1] = cvt_pk_bf16(v0[2], v0[3]);
    }
    {
      unsigned int* ph = (unsigned int*)(xb + (16 + r) * 512 + off);  // (16+r)&15 == r
      ph[0] = cvt_pk_bf16(v1[0], v1[1]);
      ph[1] = cvt_pk_bf16(v1[2], v1[3]);
    }
  }
  __syncthreads();

  // ---- two layers: out = act(X @ W^T + b); W shared across 4 batches ----
  for (int layer = 0; layer < 2; ++layer) {
    f32x16 acc0, acc1, acc2, acc3;       // [batch]
    #pragma unroll
    for (int i = 0; i < 16; ++i) { acc0[i]=0.f; acc1[i]=0.f; acc2[i]=0.f; acc3[i]=0.f; }

    const float* bl_ = layer ? g_b2 : g_b1;
    #pragma unroll
    for (int ks = 0; ks < 16; ++ks) {
      const size_t f0 = ((((size_t)layer * 16 + ks) * 8 + wid) * 64 + lane) * 8;
      s16x8 bh = *(const s16x8*)(wh + f0);
      const int aoff = (((ks << 5) + (half << 4)) ^ ((cl & 15) << 4));
      s16x8 a0 = *(const s16x8*)(sm +         cl * 512 + aoff);
      s16x8 a1 = *(const s16x8*)(sm + 16384 + cl * 512 + aoff);
      s16x8 a2 = *(const s16x8*)(sm + 32768 + cl * 512 + aoff);
      s16x8 a3 = *(const s16x8*)(sm + 49152 + cl * 512 + aoff);
      acc0 = __builtin_amdgcn_mfma_f32_32x32x16_bf16(a0, bh, acc0, 0, 0, 0);
      acc1 = __builtin_amdgcn_mfma_f32_32x32x16_bf16(a1, bh, acc1, 0, 0, 0);
      acc2 = __builtin_amdgcn_mfma_f32_32x32x16_bf16(a2, bh, acc2, 0, 0, 0);
      acc3 = __builtin_amdgcn_mfma_f32_32x32x16_bf16(a3, bh, acc3, 0, 0, 0);
    }
    __syncthreads();   // all x reads done before in-place overwrite

    const float bv  = bl_[(wid << 5) + cl];        // D col = wid*32 + cl
    const int  colb = (((wid << 5) + cl) << 1);

    if (layer == 0) {
      #pragma unroll
      for (int reg = 0; reg < 16; ++reg) {
        int rr  = (reg & 3) + ((reg >> 2) << 3) + (half << 2);
        int off = colb ^ ((rr & 15) << 4);
        *(unsigned short*)(sm +         rr * 512 + off) = cvt_bf16(fmaxf(acc0[reg] + bv, 0.f));
        *(unsigned short*)(sm + 16384 + rr * 512 + off) = cvt_bf16(fmaxf(acc1[reg] + bv, 0.f));
        *(unsigned short*)(sm + 32768 + rr * 512 + off) = cvt_bf16(fmaxf(acc2[reg] + bv, 0.f));
        *(unsigned short*)(sm + 49152 + rr * 512 + off) = cvt_bf16(fmaxf(acc3[reg] + bv, 0.f));
      }
      __syncthreads();
    } else {
      // layer 2: per-row norm partials (over wave's 32 cols) + write p-hi
      #pragma unroll
      for (int reg = 0; reg < 16; ++reg) {
        int rr  = (reg & 3) + ((reg >> 2) << 3) + (half << 2);
        int off = colb ^ ((rr & 15) << 4);
        float p0 = acc0[reg] + bv, p1 = acc1[reg] + bv;
        float p2 = acc2[reg] + bv, p3 = acc3[reg] + bv;
        float s0 = xor16_add(row16_sum(p0 * p0));
        float s1 = xor16_add(row16_sum(p1 * p1));
        float s2 = xor16_add(row16_sum(p2 * p2));
        float s3 = xor16_add(row16_sum(p3 * p3));
        if (cl == 0) {
          normL[(0 * 8 + wid) * 32 + rr] = s0;
          normL[(1 * 8 + wid) * 32 + rr] = s1;
          normL[(2 * 8 + wid) * 32 + rr] = s2;
          normL[(3 * 8 + wid) * 32 + rr] = s3;
        }
        *(unsigned short*)(sm +         rr * 512 + off) = cvt_bf16(p0);
        *(unsigned short*)(sm + 16384 + rr * 512 + off) = cvt_bf16(p1);
        *(unsigned short*)(sm + 32768 + rr * 512 + off) = cvt_bf16(p2);
        *(unsigned short*)(sm + 49152 + rr * 512 + off) = cvt_bf16(p3);
      }
      __syncthreads();
    }
  }

  // ---- G + C tail: waves 0-3 -> batches 0-3; others exit ----
  if (wid >= 4) return;
  {
    const int fr = lane & 15, fg = lane >> 4;
    char* xg = sm + wid * 16384;
    f32x4 accG = {0.f, 0.f, 0.f, 0.f};
    #pragma unroll
    for (int ks16 = 0; ks16 < 8; ++ks16) {
      int koff = ((ks16 << 6) + (fg << 4)) ^ ((fr & 15) << 4);   // (16+fr)&15 == fr
      s16x8 aq = *(const s16x8*)(xg +        fr * 512 + koff);
      s16x8 br = *(const s16x8*)(xg + (16 + fr) * 512 + koff);
      accG = __builtin_amdgcn_mfma_f32_16x16x32_bf16(aq, br, accG, 0, 0, 0);
    }
    float nr_ = 0.f;
    #pragma unroll
    for (int cg = 0; cg < 8; ++cg) nr_ += normL[(wid * 8 + cg) * 32 + 16 + fr];
    #pragma unroll
    for (int j = 0; j < 4; ++j) {
      int row = (fg << 2) + j;            // D layout: row=(lane>>4)*4+reg, col=lane&15
      float nq_ = 0.f;
      #pragma unroll
      for (int cg = 0; cg < 8; ++cg) nq_ += normL[(wid * 8 + cg) * 32 + row];
      float Cv = sqrtf(fmaxf(nq_ + nr_ - 2.0f * accG[j], 1e-6f));
      __builtin_nontemporal_store(Cv, g_out + OFF_C + (size_t)(bId0 + wid) * 256 + row * 16 + fr);
    }
  }
}

// ---------------------------------------------------------------------------
// fgw_sink: 1 wave per batch, 4 waves/block, zero barriers, 8 blocks/CU.
// Lane layout: m = lane&15 (column), k_j = 4*(lane>>4)+j (4 rows per lane).
// Base-2 log domain; static E factor (1 exp2 per u-phase); xor reduces.
// M1L overlays TtL (safe: wave-lockstep — all TtL reads precede M1L writes).
__global__ __launch_bounds__(256, 8)
void fgw_sink(const float* __restrict__ g_mq, const float* __restrict__ g_mr,
              const float* __restrict__ g_cq, const float* __restrict__ g_cr,
              const float* __restrict__ g_leps, float* __restrict__ g_out)
{
  __shared__ __align__(16) float sk[4 * 1088];
  const int tid  = threadIdx.x, lane = tid & 63, w = tid >> 6;
  const int batch = blockIdx.x * 4 + w;
  const int m = lane & 15, g = lane >> 4;
  float* L     = sk + w * 1088;
  float* SqL   = L;        float* SrL   = L + 320;
  float* TtL   = L + 640;  float* M1L   = L + 640;    // overlay
  float* lmuL  = L + 960;  float* muL   = L + 976;
  float* cqxL  = L + 992;  float* cqyL  = L + 1008;
  float* crxL  = L + 1024; float* cryL  = L + 1040;
  float* trowL = L + 1056; float* tcolL = L + 1072;

  float mqv = g_mq[(size_t)batch * 16 + m];
  float mrv = g_mr[(size_t)batch * 16 + m];
  float mu_m = mqv / (row16_sum(mqv) + 1e-8f);
  float nu_m = mrv / (row16_sum(mrv) + 1e-8f);
  float lmu_m = __logf(fmaxf(mu_m, 1e-8f));
  float lnu_m = __logf(fmaxf(nu_m, 1e-8f));
  float cqx_m = g_cq[(size_t)batch * 32 + 2 * m];
  float cqy_m = g_cq[(size_t)batch * 32 + 2 * m + 1];
  float crx_m = g_cr[(size_t)batch * 32 + 2 * m];
  float cry_m = g_cr[(size_t)batch * 32 + 2 * m + 1];
  if (g == 0) {
    lmuL[m] = lmu_m;  muL[m] = mu_m;
    cqxL[m] = cqx_m;  cqyL[m] = cqy_m;
    crxL[m] = crx_m;  cryL[m] = cry_m;
  }
  f32x4 lmu_j = *(const f32x4*)(lmuL + 4 * g);
  f32x4 mu_j  = *(const f32x4*)(muL  + 4 * g);
  f32x4 cqxj  = *(const f32x4*)(cqxL + 4 * g);
  f32x4 cqyj  = *(const f32x4*)(cqyL + 4 * g);
  f32x4 crxj  = *(const f32x4*)(crxL + 4 * g);
  f32x4 cryj  = *(const f32x4*)(cryL + 4 * g);

  float Sq2r[4], Sr2r[4];
  #pragma unroll
  for (int j = 0; j < 4; ++j) {
    float dx = cqxj[j] - cqx_m, dy = cqyj[j] - cqy_m;
    float d2 = fmaxf(dx * dx + dy * dy, 1e-6f);
    SqL[(4 * g + j) * 20 + m] = sqrtf(d2);
    Sq2r[j] = d2;
    float ex = crxj[j] - crx_m, ey = cryj[j] - cry_m;
    float e2 = fmaxf(ex * ex + ey * ey, 1e-6f);
    SrL[(4 * g + j) * 20 + m] = sqrtf(e2);
    Sr2r[j] = e2;
  }

  float C_[4];
  const float* Cp = g_out + OFF_C + (size_t)batch * 256;
  #pragma unroll
  for (int j = 0; j < 4; ++j) C_[j] = Cp[(4 * g + j) * 16 + m];
  float eps = fminf(fmaxf(__expf(g_leps[0]), 0.01f), 0.5f);
  const float inv_eps = 1.0f / eps;
  const float rho = 0.1f / (0.1f + eps);
  const float k2s = -inv_eps * LOG2E;
  float rlmu2[4];
  #pragma unroll
  for (int j = 0; j < 4; ++j) rlmu2[j] = rho * lmu_j[j] * LOG2E;
  const float rlnu2 = rho * lnu_m * LOG2E;
  float T_[4];
  #pragma unroll
  for (int j = 0; j < 4; ++j) T_[j] = mu_j[j] * nu_m;

  float Cf[4], E[4], B2[4], x2[4], v2 = 0.f;

  for (int it = 0; it < 5; ++it) {
    float trow_j[4];
    #pragma unroll
    for (int j = 0; j < 4; ++j) trow_j[j] = row16_sum(T_[j]);
    float tc = xor32_add(xor16_add(T_[0] + T_[1] + T_[2] + T_[3]));
    if (m == 0) { f32x4 tv = {trow_j[0], trow_j[1], trow_j[2], trow_j[3]};
                  *(f32x4*)(trowL + 4 * g) = tv; }
    if (g == 0) tcolL[m] = tc;
    { f32x4 tv = {T_[0], T_[1], T_[2], T_[3]};
      *(f32x4*)(TtL + m * 20 + 4 * g) = tv; }

    float trow_m = trowL[m];
    float t1_[4];
    #pragma unroll
    for (int j = 0; j < 4; ++j) t1_[j] = row16_sum(Sq2r[j] * trow_m);
    f32x4 tcv = *(const f32x4*)(tcolL + 4 * g);
    float p2 = tcv[0] * Sr2r[0] + tcv[1] * Sr2r[1] + tcv[2] * Sr2r[2] + tcv[3] * Sr2r[3];
    float t2_ = xor32_add(xor16_add(p2));

    float M1r[4] = {0.f, 0.f, 0.f, 0.f};
    #pragma unroll
    for (int l = 0; l < 16; ++l) {
      f32x4 t4 = *(const f32x4*)(TtL + l * 20 + 4 * g);
      float srv = SrL[l * 20 + m];
      M1r[0] += t4[0] * srv; M1r[1] += t4[1] * srv;
      M1r[2] += t4[2] * srv; M1r[3] += t4[3] * srv;
    }
    #pragma unroll
    for (int j = 0; j < 4; ++j) M1L[(4 * g + j) * 20 + m] = M1r[j];
    float t3_[4] = {0.f, 0.f, 0.f, 0.f};
    #pragma unroll
    for (int l = 0; l < 16; ++l) {
      f32x4 sq4 = *(const f32x4*)(SqL + l * 20 + 4 * g);
      float m1v = M1L[l * 20 + m];
      t3_[0] += sq4[0] * m1v; t3_[1] += sq4[1] * m1v;
      t3_[2] += sq4[2] * m1v; t3_[3] += sq4[3] * m1v;
    }

    #pragma unroll
    for (int j = 0; j < 4; ++j) {
      float lgw = t1_[j] + t2_ - 2.0f * t3_[j];
      Cf[j] = 0.5f * C_[j] + 0.5f * lgw;
      float lk2 = k2s * Cf[j];                 // logK * log2e
      float mx2 = row16_max(lk2);              // static row shift
      E[j]  = fexp2(lk2 - mx2);                // in (0,1], row max = 1
      B2[j] = lk2 + rlmu2[j] - rho * mx2;      // logK2 + rho*(lmu2 - Mx2)
    }

    v2 = 0.f;
    #pragma unroll 1
    for (int s = 0; s < 10; ++s) {
      // u-phase: s_j = sum_m E[j]*2^v2 ; x2 = logK2+u2 = B2 - rho*log2(s_j)
      float ev = fexp2(v2);
      #pragma unroll
      for (int j = 0; j < 4; ++j) {
        float sj = row16_sum(E[j] * ev);
        x2[j] = B2[j] - rho * flog2(sj);
      }
      // v-phase: v2 = rlnu2 - rho*log2(sum_k 2^x2)   (dynamic max, safe)
      float mx = fmaxf(fmaxf(x2[0], x2[1]), fmaxf(x2[2], x2[3]));
      mx = xor32_max(xor16_max(mx));
      float ss = fexp2(x2[0] - mx) + fexp2(x2[1] - mx)
               + fexp2(x2[2] - mx) + fexp2(x2[3] - mx);
      ss = xor32_add(xor16_add(ss));
      v2 = rlnu2 - rho * (mx + flog2(ss));
    }
    #pragma unroll
    for (int j = 0; j < 4; ++j) T_[j] = fexp2(x2[j] + v2);
  }

  float cp = T_[0] * Cf[0] + T_[1] * Cf[1] + T_[2] * Cf[2] + T_[3] * Cf[3];
  cp = xor32_add(xor16_add(row16_sum(cp)));
  float* To = g_out + OFF_T + (size_t)batch * 256;
  #pragma unroll
  for (int j = 0; j < 4; ++j)
    __builtin_nontemporal_store(T_[j], To + (4 * g + j) * 16 + m);
  if (lane == 0) {
    g_out[batch] = 1.0f / (1.0f + __expf(cp));   // sigmoid(-cost)
    g_out[OFF_CST + batch] = cp;
  }
}

extern "C" void kernel_launch(void* const* d_in, const int* in_sizes, int n_in,
                              void* d_out, int out_size, void* d_ws, size_t ws_size,
                              hipStream_t stream) {
  (void)in_sizes; (void)n_in; (void)out_size; (void)ws_size;
  unsigned int*   wh32 = (unsigned int*)d_ws;      // 262,144 B
  unsigned short* wh   = (unsigned short*)wh32;

  prep_w32<<<dim3(64), dim3(256), 0, stream>>>(
      (const float*)d_in[6], (const float*)d_in[8], wh32);
  fgw_proj<<<dim3(2048), dim3(512), 0, stream>>>(
      (const float*)d_in[0], (const float*)d_in[1], wh,
      (const float*)d_in[7], (const float*)d_in[9], (float*)d_out);
  fgw_sink<<<dim3(2048), dim3(256), 0, stream>>>(
      (const float*)d_in[2], (const float*)d_in[3],
      (const float*)d_in[4], (const float*)d_in[5],
      (const float*)d_in[10], (float*)d_out);
}

// Round 18
// 191.421 us; speedup vs baseline: 1.0715x; 1.0715x over previous
//
#include <hip/hip_runtime.h>

// FusedGromovWasserstein — 3 kernels:
//  prep_w32: W1,W2 f32 -> bf16-hi 32x32x16-MFMA B-fragments in d_ws
//  fgw_proj: 2 batches/block, 256 thr (4 waves); wave = 2 colgroups x 2
//            batches (A ds_read shared across cg-pair -> A-LDS-reads halved);
//            mfma_32x32x16 (x-hi, W-hi); cvt_pk; (row&15) XOR swizzle;
//            G+C tail in waves 0-1.
//  fgw_sink: 1 wave/batch, barrier-free, 8 blocks/CU; base-2 log domain,
//            static E + static per-outer col-max mxB (no per-iter cross-lane
//            max); xor16/xor32 sums only.
// Outputs flat: [sigmoid(-cost) 8192][T 8192*256][C 8192*256][cost 8192].

#define OFF_T   8192
#define OFF_C   2105344
#define OFF_CST 4202496

typedef float  f32x4  __attribute__((ext_vector_type(4)));
typedef float  f32x16 __attribute__((ext_vector_type(16)));
typedef short  s16x8  __attribute__((ext_vector_type(8)));

#define LOG2E 1.4426950408889634f

// native v_exp_f32 (2^x) / v_log_f32 (log2 x)
__device__ __forceinline__ float fexp2(float x) { return __builtin_amdgcn_exp2f(x); }
__device__ __forceinline__ float flog2(float x) { return __builtin_amdgcn_logf(x); }

// v_cvt_pk_bf16_f32: RNE, 1 VALU for 2 values (no builtin on gfx950 — T12)
__device__ __forceinline__ unsigned int cvt_pk_bf16(float lo, float hi) {
  unsigned int r;
  asm("v_cvt_pk_bf16_f32 %0, %1, %2" : "=v"(r) : "v"(lo), "v"(hi));
  return r;
}
__device__ __forceinline__ unsigned short cvt_bf16(float x) {
  unsigned int r;
  asm("v_cvt_pk_bf16_f32 %0, %1, %2" : "=v"(r) : "v"(x), "v"(x));
  return (unsigned short)r;
}

// ---- cross-lane reduction helpers ----
template <int CTRL>
__device__ __forceinline__ float dpp_add(float x) {
  return x + __int_as_float(__builtin_amdgcn_update_dpp(
      0, __float_as_int(x), CTRL, 0xf, 0xf, true));
}
template <int CTRL>
__device__ __forceinline__ float dpp_max(float x) {
  return fmaxf(x, __int_as_float(__builtin_amdgcn_update_dpp(
      0, __float_as_int(x), CTRL, 0xf, 0xf, true)));
}
__device__ __forceinline__ float row16_sum(float x) {
  x = dpp_add<0xB1>(x);  x = dpp_add<0x4E>(x);
  x = dpp_add<0x124>(x); x = dpp_add<0x128>(x);
  return x;
}
__device__ __forceinline__ float row16_max(float x) {
  x = dpp_max<0xB1>(x);  x = dpp_max<0x4E>(x);
  x = dpp_max<0x124>(x); x = dpp_max<0x128>(x);
  return x;
}
__device__ __forceinline__ float xor16_add(float x) {
  return x + __int_as_float(__builtin_amdgcn_ds_swizzle(__float_as_int(x), 0x401F));
}
__device__ __forceinline__ float xor16_max(float x) {
  return fmaxf(x, __int_as_float(__builtin_amdgcn_ds_swizzle(__float_as_int(x), 0x401F)));
}
__device__ __forceinline__ float xor32_add(float x) { return x + __shfl_xor(x, 32); }
__device__ __forceinline__ float xor32_max(float x) { return fmaxf(x, __shfl_xor(x, 32)); }

// ---------------------------------------------------------------------------
// prep_w32: 16384 hi fragments (2 layers x 16 ksteps x 8 colgroups x 64 lanes).
// Fragment fid holds W[col = cg*32 + (lane&31)][k = s*16 + (lane>>5)*8 + e].
__global__ __launch_bounds__(256, 1)
void prep_w32(const float* __restrict__ W1, const float* __restrict__ W2,
              unsigned int* __restrict__ wh)
{
  const int fid  = blockIdx.x * 256 + threadIdx.x;   // 0..16383
  const int l    = fid >> 13;
  const int s    = (fid >> 9) & 15;
  const int cg   = (fid >> 6) & 7;
  const int lane = fid & 63;
  const int col  = cg * 32 + (lane & 31);
  const int k0   = s * 16 + ((lane >> 5) << 3);
  const float* W = l ? W2 : W1;
  const float* src = W + ((size_t)col << 8) + k0;
  float4 a = *(const float4*)src;
  float4 b = *(const float4*)(src + 4);
  uint4 vh = {cvt_pk_bf16(a.x, a.y), cvt_pk_bf16(a.z, a.w),
              cvt_pk_bf16(b.x, b.y), cvt_pk_bf16(b.z, b.w)};
  ((uint4*)wh)[fid] = vh;
}

// ---------------------------------------------------------------------------
// fgw_proj: 2 batches/block, 256 threads (4 waves). LDS: 2 x 16KB x-hi tiles
// (rows 0-15 q, 16-31 r; row stride 512B; XOR swizzle ((row&15)<<4)),
// normL [2][4][32] f32 at float idx 8192.
// Wave wid ∈ 0..3 = cg pair {2wid, 2wid+1}, both batches.
// Per ks: 2 W L2-loads + 2 A ds_reads (shared by cg pair) + 4 MFMA.
__global__ __launch_bounds__(256, 3)
void fgw_proj(const float* __restrict__ g_q,  const float* __restrict__ g_r,
              const unsigned short* __restrict__ wh,
              const float* __restrict__ g_b1, const float* __restrict__ g_b2,
              float* __restrict__ g_out)
{
  __shared__ __align__(16) float smemf[8448];    // 33,792 B
  char* sm = (char*)smemf;
  float* normL = smemf + 8192;                   // [2][4][32]
  const int bId0 = blockIdx.x * 2;
  const int tid  = threadIdx.x;
  const int lane = tid & 63, wid = tid >> 6;     // wid 0..3 = cg pair
  const int cl   = lane & 31, half = lane >> 5;  // A-row / D-col, k-half
  const int cg0  = (wid << 1), cg1 = (wid << 1) + 1;

  // ---- stage 2 batches as bf16-hi; non-temporal (read-once stream) ----
  #pragma unroll
  for (int j = 0; j < 8; ++j) {
    int idx = (j << 8) + tid;          // 0..2047
    int bb  = idx >> 10;
    int t   = idx & 1023;
    int r   = t >> 6;                  // row 0..15
    int sg  = t & 63;                  // float4 segment
    int off = ((sg << 3) ^ ((r & 15) << 4));
    char* xb = sm + bb * 16384;
    const f32x4* xq = (const f32x4*)(g_q + (size_t)(bId0 + bb) * 4096 + (r << 8) + (sg << 2));
    const f32x4* xr = (const f32x4*)(g_r + (size_t)(bId0 + bb) * 4096 + (r << 8) + (sg << 2));
    f32x4 v0 = __builtin_nontemporal_load(xq);
    f32x4 v1 = __builtin_nontemporal_load(xr);
    {
      unsigned int* ph = (unsigned int*)(xb + r * 512 + off);
      ph[0] = cvt_pk_bf16(v0[0], v0[1]);
      ph[1] = cvt_pk_bf16(v0[2], v0[3]);
    }
    {
      unsigned int* ph = (unsigned int*)(xb + (16 + r) * 512 + off);  // (16+r)&15 == r
      ph[0] = cvt_pk_bf16(v1[0], v1[1]);
      ph[1] = cvt_pk_bf16(v1[2], v1[3]);
    }
  }
  __syncthreads();

  // ---- two layers: out = act(X @ W^T + b) ----
  for (int layer = 0; layer < 2; ++layer) {
    f32x16 acc00, acc01, acc10, acc11;   // [batch][cg]
    #pragma unroll
    for (int i = 0; i < 16; ++i) { acc00[i]=0.f; acc01[i]=0.f; acc10[i]=0.f; acc11[i]=0.f; }

    const float* bl_ = layer ? g_b2 : g_b1;
    #pragma unroll
    for (int ks = 0; ks < 16; ++ks) {
      const size_t f0 = ((((size_t)layer * 16 + ks) * 8 + cg0) * 64 + lane) * 8;
      s16x8 w0 = *(const s16x8*)(wh + f0);
      s16x8 w1 = *(const s16x8*)(wh + f0 + 512);   // cg1 = cg0+1 -> +512 shorts
      const int aoff = (((ks << 5) + (half << 4)) ^ ((cl & 15) << 4));
      s16x8 a0 = *(const s16x8*)(sm +         cl * 512 + aoff);
      s16x8 a1 = *(const s16x8*)(sm + 16384 + cl * 512 + aoff);
      acc00 = __builtin_amdgcn_mfma_f32_32x32x16_bf16(a0, w0, acc00, 0, 0, 0);
      acc01 = __builtin_amdgcn_mfma_f32_32x32x16_bf16(a0, w1, acc01, 0, 0, 0);
      acc10 = __builtin_amdgcn_mfma_f32_32x32x16_bf16(a1, w0, acc10, 0, 0, 0);
      acc11 = __builtin_amdgcn_mfma_f32_32x32x16_bf16(a1, w1, acc11, 0, 0, 0);
    }
    __syncthreads();   // all x reads done before in-place overwrite

    const float bv0  = bl_[(cg0 << 5) + cl];
    const float bv1  = bl_[(cg1 << 5) + cl];
    const int colb0  = (((cg0 << 5) + cl) << 1);
    const int colb1  = (((cg1 << 5) + cl) << 1);

    if (layer == 0) {
      #pragma unroll
      for (int reg = 0; reg < 16; ++reg) {
        int rr   = (reg & 3) + ((reg >> 2) << 3) + (half << 2);
        int off0 = colb0 ^ ((rr & 15) << 4);
        int off1 = colb1 ^ ((rr & 15) << 4);
        *(unsigned short*)(sm +         rr * 512 + off0) = cvt_bf16(fmaxf(acc00[reg] + bv0, 0.f));
        *(unsigned short*)(sm +         rr * 512 + off1) = cvt_bf16(fmaxf(acc01[reg] + bv1, 0.f));
        *(unsigned short*)(sm + 16384 + rr * 512 + off0) = cvt_bf16(fmaxf(acc10[reg] + bv0, 0.f));
        *(unsigned short*)(sm + 16384 + rr * 512 + off1) = cvt_bf16(fmaxf(acc11[reg] + bv1, 0.f));
      }
      __syncthreads();
    } else {
      // layer 2: per-row norm partials (over wave's 64 cols) + write p-hi
      #pragma unroll
      for (int reg = 0; reg < 16; ++reg) {
        int rr   = (reg & 3) + ((reg >> 2) << 3) + (half << 2);
        int off0 = colb0 ^ ((rr & 15) << 4);
        int off1 = colb1 ^ ((rr & 15) << 4);
        float p00 = acc00[reg] + bv0, p01 = acc01[reg] + bv1;
        float p10 = acc10[reg] + bv0, p11 = acc11[reg] + bv1;
        float s0 = xor16_add(row16_sum(p00 * p00 + p01 * p01));
        float s1 = xor16_add(row16_sum(p10 * p10 + p11 * p11));
        if (cl == 0) {
          normL[(0 * 4 + wid) * 32 + rr] = s0;
          normL[(1 * 4 + wid) * 32 + rr] = s1;
        }
        *(unsigned short*)(sm +         rr * 512 + off0) = cvt_bf16(p00);
        *(unsigned short*)(sm +         rr * 512 + off1) = cvt_bf16(p01);
        *(unsigned short*)(sm + 16384 + rr * 512 + off0) = cvt_bf16(p10);
        *(unsigned short*)(sm + 16384 + rr * 512 + off1) = cvt_bf16(p11);
      }
      __syncthreads();
    }
  }

  // ---- G + C tail: wave 0 -> batch 0, wave 1 -> batch 1; others exit ----
  if (wid >= 2) return;
  {
    const int fr = lane & 15, fg = lane >> 4;
    char* xg = sm + wid * 16384;
    f32x4 accG = {0.f, 0.f, 0.f, 0.f};
    #pragma unroll
    for (int ks16 = 0; ks16 < 8; ++ks16) {
      int koff = ((ks16 << 6) + (fg << 4)) ^ ((fr & 15) << 4);   // (16+fr)&15 == fr
      s16x8 aq = *(const s16x8*)(xg +        fr * 512 + koff);
      s16x8 br = *(const s16x8*)(xg + (16 + fr) * 512 + koff);
      accG = __builtin_amdgcn_mfma_f32_16x16x32_bf16(aq, br, accG, 0, 0, 0);
    }
    float nr_ = 0.f;
    #pragma unroll
    for (int cg = 0; cg < 4; ++cg) nr_ += normL[(wid * 4 + cg) * 32 + 16 + fr];
    #pragma unroll
    for (int j = 0; j < 4; ++j) {
      int row = (fg << 2) + j;            // D layout: row=(lane>>4)*4+reg, col=lane&15
      float nq_ = 0.f;
      #pragma unroll
      for (int cg = 0; cg < 4; ++cg) nq_ += normL[(wid * 4 + cg) * 32 + row];
      float Cv = sqrtf(fmaxf(nq_ + nr_ - 2.0f * accG[j], 1e-6f));
      __builtin_nontemporal_store(Cv, g_out + OFF_C + (size_t)(bId0 + wid) * 256 + row * 16 + fr);
    }
  }
}

// ---------------------------------------------------------------------------
// fgw_sink: 1 wave per batch, 4 waves/block, zero barriers, 8 blocks/CU.
// Lane layout: m = lane&15 (column), k_j = 4*(lane>>4)+j (4 rows per lane).
// Base-2 log domain; static E (1 exp2 per u-phase); static per-outer
// col-max mxB for the v-phase LSE shift (LSE is shift-exact; correction
// |rho*log2 s| bounded -> no overflow at 2^(x-mxB)).
// M1L overlays TtL (safe: wave-lockstep — all TtL reads precede M1L writes).
__global__ __launch_bounds__(256, 8)
void fgw_sink(const float* __restrict__ g_mq, const float* __restrict__ g_mr,
              const float* __restrict__ g_cq, const float* __restrict__ g_cr,
              const float* __restrict__ g_leps, float* __restrict__ g_out)
{
  __shared__ __align__(16) float sk[4 * 1088];
  const int tid  = threadIdx.x, lane = tid & 63, w = tid >> 6;
  const int batch = blockIdx.x * 4 + w;
  const int m = lane & 15, g = lane >> 4;
  float* L     = sk + w * 1088;
  float* SqL   = L;        float* SrL   = L + 320;
  float* TtL   = L + 640;  float* M1L   = L + 640;    // overlay
  float* lmuL  = L + 960;  float* muL   = L + 976;
  float* cqxL  = L + 992;  float* cqyL  = L + 1008;
  float* crxL  = L + 1024; float* cryL  = L + 1040;
  float* trowL = L + 1056; float* tcolL = L + 1072;

  float mqv = g_mq[(size_t)batch * 16 + m];
  float mrv = g_mr[(size_t)batch * 16 + m];
  float mu_m = mqv / (row16_sum(mqv) + 1e-8f);
  float nu_m = mrv / (row16_sum(mrv) + 1e-8f);
  float lmu_m = __logf(fmaxf(mu_m, 1e-8f));
  float lnu_m = __logf(fmaxf(nu_m, 1e-8f));
  float cqx_m = g_cq[(size_t)batch * 32 + 2 * m];
  float cqy_m = g_cq[(size_t)batch * 32 + 2 * m + 1];
  float crx_m = g_cr[(size_t)batch * 32 + 2 * m];
  float cry_m = g_cr[(size_t)batch * 32 + 2 * m + 1];
  if (g == 0) {
    lmuL[m] = lmu_m;  muL[m] = mu_m;
    cqxL[m] = cqx_m;  cqyL[m] = cqy_m;
    crxL[m] = crx_m;  cryL[m] = cry_m;
  }
  f32x4 lmu_j = *(const f32x4*)(lmuL + 4 * g);
  f32x4 mu_j  = *(const f32x4*)(muL  + 4 * g);
  f32x4 cqxj  = *(const f32x4*)(cqxL + 4 * g);
  f32x4 cqyj  = *(const f32x4*)(cqyL + 4 * g);
  f32x4 crxj  = *(const f32x4*)(crxL + 4 * g);
  f32x4 cryj  = *(const f32x4*)(cryL + 4 * g);

  float Sq2r[4], Sr2r[4];
  #pragma unroll
  for (int j = 0; j < 4; ++j) {
    float dx = cqxj[j] - cqx_m, dy = cqyj[j] - cqy_m;
    float d2 = fmaxf(dx * dx + dy * dy, 1e-6f);
    SqL[(4 * g + j) * 20 + m] = sqrtf(d2);
    Sq2r[j] = d2;
    float ex = crxj[j] - crx_m, ey = cryj[j] - cry_m;
    float e2 = fmaxf(ex * ex + ey * ey, 1e-6f);
    SrL[(4 * g + j) * 20 + m] = sqrtf(e2);
    Sr2r[j] = e2;
  }

  float C_[4];
  const float* Cp = g_out + OFF_C + (size_t)batch * 256;
  #pragma unroll
  for (int j = 0; j < 4; ++j) C_[j] = Cp[(4 * g + j) * 16 + m];
  float eps = fminf(fmaxf(__expf(g_leps[0]), 0.01f), 0.5f);
  const float inv_eps = 1.0f / eps;
  const float rho = 0.1f / (0.1f + eps);
  const float k2s = -inv_eps * LOG2E;
  float rlmu2[4];
  #pragma unroll
  for (int j = 0; j < 4; ++j) rlmu2[j] = rho * lmu_j[j] * LOG2E;
  const float rlnu2 = rho * lnu_m * LOG2E;
  float T_[4];
  #pragma unroll
  for (int j = 0; j < 4; ++j) T_[j] = mu_j[j] * nu_m;

  float Cf[4], E[4], B2[4], x2[4], v2 = 0.f;

  for (int it = 0; it < 5; ++it) {
    float trow_j[4];
    #pragma unroll
    for (int j = 0; j < 4; ++j) trow_j[j] = row16_sum(T_[j]);
    float tc = xor32_add(xor16_add(T_[0] + T_[1] + T_[2] + T_[3]));
    if (m == 0) { f32x4 tv = {trow_j[0], trow_j[1], trow_j[2], trow_j[3]};
                  *(f32x4*)(trowL + 4 * g) = tv; }
    if (g == 0) tcolL[m] = tc;
    { f32x4 tv = {T_[0], T_[1], T_[2], T_[3]};
      *(f32x4*)(TtL + m * 20 + 4 * g) = tv; }

    float trow_m = trowL[m];
    float t1_[4];
    #pragma unroll
    for (int j = 0; j < 4; ++j) t1_[j] = row16_sum(Sq2r[j] * trow_m);
    f32x4 tcv = *(const f32x4*)(tcolL + 4 * g);
    float p2 = tcv[0] * Sr2r[0] + tcv[1] * Sr2r[1] + tcv[2] * Sr2r[2] + tcv[3] * Sr2r[3];
    float t2_ = xor32_add(xor16_add(p2));

    float M1r[4] = {0.f, 0.f, 0.f, 0.f};
    #pragma unroll
    for (int l = 0; l < 16; ++l) {
      f32x4 t4 = *(const f32x4*)(TtL + l * 20 + 4 * g);
      float srv = SrL[l * 20 + m];
      M1r[0] += t4[0] * srv; M1r[1] += t4[1] * srv;
      M1r[2] += t4[2] * srv; M1r[3] += t4[3] * srv;
    }
    #pragma unroll
    for (int j = 0; j < 4; ++j) M1L[(4 * g + j) * 20 + m] = M1r[j];
    float t3_[4] = {0.f, 0.f, 0.f, 0.f};
    #pragma unroll
    for (int l = 0; l < 16; ++l) {
      f32x4 sq4 = *(const f32x4*)(SqL + l * 20 + 4 * g);
      float m1v = M1L[l * 20 + m];
      t3_[0] += sq4[0] * m1v; t3_[1] += sq4[1] * m1v;
      t3_[2] += sq4[2] * m1v; t3_[3] += sq4[3] * m1v;
    }

    #pragma unroll
    for (int j = 0; j < 4; ++j) {
      float lgw = t1_[j] + t2_ - 2.0f * t3_[j];
      Cf[j] = 0.5f * C_[j] + 0.5f * lgw;
      float lk2 = k2s * Cf[j];                 // logK * log2e
      float mx2 = row16_max(lk2);              // static row shift
      E[j]  = fexp2(lk2 - mx2);                // in (0,1], row max = 1
      B2[j] = lk2 + rlmu2[j] - rho * mx2;      // logK2 + rho*(lmu2 - Mx2)
    }
    // static per-outer column max of B2 (over all 16 k, per column m)
    float mxB = fmaxf(fmaxf(B2[0], B2[1]), fmaxf(B2[2], B2[3]));
    mxB = xor32_max(xor16_max(mxB));

    v2 = 0.f;
    #pragma unroll 1
    for (int s = 0; s < 10; ++s) {
      // u-phase: s_j = sum_m E[j]*2^v2 ; x2 = logK2+u2 = B2 - rho*log2(s_j)
      float ev = fexp2(v2);
      #pragma unroll
      for (int j = 0; j < 4; ++j) {
        float sj = row16_sum(E[j] * ev);
        x2[j] = B2[j] - rho * flog2(sj);
      }
      // v-phase: v2 = rlnu2 - rho*(mxB + log2(sum_k 2^(x2-mxB)))  (static shift)
      float ss = fexp2(x2[0] - mxB) + fexp2(x2[1] - mxB)
               + fexp2(x2[2] - mxB) + fexp2(x2[3] - mxB);
      ss = xor32_add(xor16_add(ss));
      v2 = rlnu2 - rho * (mxB + flog2(ss));
    }
    #pragma unroll
    for (int j = 0; j < 4; ++j) T_[j] = fexp2(x2[j] + v2);
  }

  float cp = T_[0] * Cf[0] + T_[1] * Cf[1] + T_[2] * Cf[2] + T_[3] * Cf[3];
  cp = xor32_add(xor16_add(row16_sum(cp)));
  float* To = g_out + OFF_T + (size_t)batch * 256;
  #pragma unroll
  for (int j = 0; j < 4; ++j)
    __builtin_nontemporal_store(T_[j], To + (4 * g + j) * 16 + m);
  if (lane == 0) {
    g_out[batch] = 1.0f / (1.0f + __expf(cp));   // sigmoid(-cost)
    g_out[OFF_CST + batch] = cp;
  }
}

extern "C" void kernel_launch(void* const* d_in, const int* in_sizes, int n_in,
                              void* d_out, int out_size, void* d_ws, size_t ws_size,
                              hipStream_t stream) {
  (void)in_sizes; (void)n_in; (void)out_size; (void)ws_size;
  unsigned int*   wh32 = (unsigned int*)d_ws;      // 262,144 B
  unsigned short* wh   = (unsigned short*)wh32;

  prep_w32<<<dim3(64), dim3(256), 0, stream>>>(
      (const float*)d_in[6], (const float*)d_in[8], wh32);
  fgw_proj<<<dim3(4096), dim3(256), 0, stream>>>(
      (const float*)d_in[0], (const float*)d_in[1], wh,
      (const float*)d_in[7], (const float*)d_in[9], (float*)d_out);
  fgw_sink<<<dim3(2048), dim3(256), 0, stream>>>(
      (const float*)d_in[2], (const float*)d_in[3],
      (const float*)d_in[4], (const float*)d_in[5],
      (const float*)d_in[10], (float*)d_out);
}